// Round 12
// baseline (136.634 us; speedup 1.0000x reference)
//
#include <hip/hip_runtime.h>
#include <stdint.h>

#define NTETS   200000
#define FEATS   128
#define OUTF    128
#define NG      5
#define BM      128
#define NTHR    512
#define NTILES  ((NTETS + BM - 1) / BM)   // 1563
#define NPBLK   768                       // persistent blocks = 3/CU x 256 CU
#define SUBS    10                        // K=64 sub-chunks
#define SUBW    16384                     // W bytes per sub-chunk

typedef __attribute__((ext_vector_type(8))) short  short8v;
typedef __attribute__((ext_vector_type(4))) float  f32x4;

static __device__ __forceinline__ unsigned short bf16_rne(float f) {
  union { float f; unsigned u; } v; v.f = f;
  unsigned r = v.u + 0x7FFFu + ((v.u >> 16) & 1u);
  return (unsigned short)(r >> 16);
}

static __device__ __forceinline__ void gload_lds16(const void* g, void* l) {
  __builtin_amdgcn_global_load_lds(
      (const __attribute__((address_space(1))) unsigned int*)g,
      (__attribute__((address_space(3))) unsigned int*)l, 16, 0, 0);
}

// Merged prep: blocks 0..319 build the W fragment image; block 320 detects
// int64-vs-int32 neighbor storage and zeroes the dynamic tile counter.
// W image [g][kk][ns8][lane64][e8]: byte ((g*4+kk)*8+ns)*1024 + lane*16 is
// lane's mfma_16x16x32 B-fragment (n = ns*16+(lane&15), k = g*128+kk*32+(lane>>4)*8+e).
__global__ void prep_meta_k(const float* __restrict__ W, unsigned short* __restrict__ wf,
                            const int* __restrict__ nbr, int* __restrict__ mode,
                            unsigned* __restrict__ counter) {
  int b = blockIdx.x;
  if (b == 320) {
    int t = threadIdx.x;
    if (t < 64) {
      int nz = 0;
      for (int i = t; i < 4096; i += 64) nz |= nbr[2 * i + 1];
      unsigned long long any = __ballot(nz != 0);
      if (t == 0) { mode[0] = (any == 0ULL) ? 1 : 0; counter[0] = 0u; }
    }
    return;
  }
  int id = b * 256 + threadIdx.x;           // 320*256 == NG*16384 exactly
  int e  = id & 7;
  int l6 = (id >> 3) & 63;
  int ns = (id >> 9) & 7;
  int kk = (id >> 12) & 3;
  int g  = id >> 14;
  int n = ns * 16 + (l6 & 15);
  int k = g * 128 + kk * 32 + (l6 >> 4) * 8 + e;
  wf[id] = bf16_rne(W[n * (NG * FEATS) + k]);
}

// features fp32 -> linear bf16 image; nt loads keep fp32 feat out of L3.
__global__ __launch_bounds__(256) void prep_f_k(const float* __restrict__ feat,
                                                unsigned short* __restrict__ fimg) {
  size_t i = ((size_t)blockIdx.x * 256 + threadIdx.x) * 8;
  f32x4 a = __builtin_nontemporal_load((const f32x4*)(feat + i));
  f32x4 b = __builtin_nontemporal_load((const f32x4*)(feat + i + 4));
  short8v v;
  v[0] = (short)bf16_rne(a[0]); v[1] = (short)bf16_rne(a[1]);
  v[2] = (short)bf16_rne(a[2]); v[3] = (short)bf16_rne(a[3]);
  v[4] = (short)bf16_rne(b[0]); v[5] = (short)bf16_rne(b[1]);
  v[6] = (short)bf16_rne(b[2]); v[7] = (short)bf16_rne(b[3]);
  *(short8v*)(fimg + i) = v;
}

__global__ __launch_bounds__(NTHR, 6) void conv_k(
    const unsigned short* __restrict__ fimg, const int* __restrict__ nbr,
    const float* __restrict__ bias, const unsigned short* __restrict__ wf,
    const int* __restrict__ mode, unsigned* __restrict__ counter,
    float* __restrict__ out)
{
  __shared__ __align__(16) char wtile[3][SUBW];   // W sub-chunk ring
  __shared__ unsigned srcoff[NG][BM];
  __shared__ unsigned tile_s;

  const int t    = threadIdx.x;
  const int lane = t & 63;
  const int wv   = t >> 6;          // 8 waves; wave wv owns rows [wv*16, wv*16+16)
  const int lr   = lane & 15;
  const int lk   = lane >> 4;
  const bool m64 = (mode[0] != 0);
  const char* fimgc = (const char*)fimg;

#define SB() __builtin_amdgcn_sched_barrier(0)

  // wave stages 2KB of the 16KB W sub-chunk (DMA builtin, un-sinkable)
#define W_ISSUE(ss) do {                                                         \
    const char* ws_ = (const char*)wf + (size_t)(ss) * SUBW + wv * 2048 +        \
                      (lane << 4);                                               \
    char* wd_ = &wtile[(ss) % 3][wv * 2048];                                     \
    gload_lds16(ws_, wd_);                                                       \
    gload_lds16(ws_ + 1024, wd_ + 1024);                                         \
  } while (0)

  for (;;) {
    if (t == 0) tile_s = atomicAdd(counter, 1u);
    __syncthreads();                        // also protects wtile/srcoff reuse
    const unsigned tile = tile_s;
    if (tile >= (unsigned)NTILES) break;
    const int row0 = (int)tile * BM;

    // ---- per-tile source byte-offsets into fimg ----
    for (int e = t; e < NG * BM; e += NTHR) {
      int g = e >> 7, r = e & (BM - 1);
      int gr = row0 + r;
      int s = 0;
      if (gr < NTETS) {
        if (g == 0) s = gr;
        else {
          size_t idx = (size_t)gr * 4 + (g - 1);
          s = m64 ? nbr[2 * idx] : nbr[idx];
          if ((unsigned)s >= (unsigned)NTETS) s = 0;
        }
      }
      srcoff[g][r] = (unsigned)s * 256u;
    }
    __syncthreads();

    // lane's A-fragment base: row (wv*16+(l&15)), byte (l>>4)*16 within the row
    unsigned aoff[NG];
#pragma unroll
    for (int g = 0; g < NG; ++g)
      aoff[g] = srcoff[g][wv * 16 + lr] + (unsigned)(lk * 16);

    const f32x4 zero = {0.f, 0.f, 0.f, 0.f};
    f32x4 acc[8];
#pragma unroll
    for (int i = 0; i < 8; ++i) acc[i] = zero;

    // ---- prologue: W ring 2 ahead ----
    W_ISSUE(0); SB();
    W_ISSUE(1); SB();
    asm volatile("s_waitcnt vmcnt(2)" ::: "memory");  // W0 landed, W1 in flight
    SB();
    __builtin_amdgcn_s_barrier();
    SB();

#pragma unroll
    for (int s = 0; s < SUBS; ++s) {
      if (s + 2 < SUBS) { W_ISSUE(s + 2); SB(); }

      // compute sub s: A at-use (compiler-waited), b from wtile[s%3]
      const char* wt = wtile[s % 3];
      const unsigned ab = aoff[s >> 1] + (unsigned)((s & 1) * 128);
      short8v a0 = *(const short8v*)(fimgc + ab);
      short8v a1 = *(const short8v*)(fimgc + ab + 64);
      {
        short8v b[8];
#pragma unroll
        for (int ns = 0; ns < 8; ++ns)
          b[ns] = *(const short8v*)(&wt[ns * 1024 + (lane << 4)]);
#pragma unroll
        for (int ns = 0; ns < 8; ++ns)
          acc[ns] = __builtin_amdgcn_mfma_f32_16x16x32_bf16(a0, b[ns], acc[ns], 0, 0, 0);
#pragma unroll
        for (int ns = 0; ns < 8; ++ns)
          b[ns] = *(const short8v*)(&wt[(8 + ns) * 1024 + (lane << 4)]);
#pragma unroll
        for (int ns = 0; ns < 8; ++ns)
          acc[ns] = __builtin_amdgcn_mfma_f32_16x16x32_bf16(a1, b[ns], acc[ns], 0, 0, 0);
      }
      SB();

      // W-only ledger: retire W(s+1) before the next sub reads it
      if (s + 2 < SUBS)      { asm volatile("s_waitcnt vmcnt(2)" ::: "memory"); }
      else if (s + 1 < SUBS) { asm volatile("s_waitcnt vmcnt(0)" ::: "memory"); }
      if (s + 1 < SUBS) {
        SB();
        __builtin_amdgcn_s_barrier();
        SB();
      }
    }

    // ---- epilogue: bias + relu + nt fp32 store (C: col=lane&15, row=(lane>>4)*4+reg) ----
#pragma unroll
    for (int ns = 0; ns < 8; ++ns) {
      const int col = ns * 16 + lr;
      const float bv = bias[col];
      const int rbase = row0 + wv * 16 + lk * 4;
#pragma unroll
      for (int i = 0; i < 4; ++i) {
        int r = rbase + i;
        if (r < NTETS) {
          float vv = acc[ns][i] + bv;
          vv = vv > 0.f ? vv : 0.f;
          __builtin_nontemporal_store(vv, &out[(size_t)r * OUTF + col]);
        }
      }
    }
  }
#undef W_ISSUE
#undef SB
}

extern "C" void kernel_launch(void* const* d_in, const int* in_sizes, int n_in,
                              void* d_out, int out_size, void* d_ws, size_t ws_size,
                              hipStream_t stream) {
  const float* feat = (const float*)d_in[0];
  const int*   nbr  = (const int*)d_in[1];
  const float* W    = (const float*)d_in[2];
  const float* bias = (const float*)d_in[3];
  float* out = (float*)d_out;

  int*      mode    = (int*)d_ws;
  unsigned* counter = (unsigned*)((char*)d_ws + 64);
  unsigned short* wf   = (unsigned short*)((char*)d_ws + 1024);     // 160 KB frag image
  unsigned short* fimg = (unsigned short*)((char*)d_ws + 164864);   // 51.2 MB bf16 features

  prep_meta_k<<<321, 256, 0, stream>>>(W, wf, nbr, mode, counter);
  prep_f_k<<<(NTETS * FEATS / 8 + 255) / 256, 256, 0, stream>>>(feat, fimg);
  conv_k<<<NPBLK, NTHR, 0, stream>>>(fimg, nbr, bias, wf, mode, counter, out);
}

// Round 13
// 103.939 us; speedup vs baseline: 1.3146x; 1.3146x over previous
//
#include <hip/hip_runtime.h>
#include <stdint.h>

#define NTETS   200000
#define FEATS   128
#define OUTF    128
#define NG      5
#define BM      128
#define NTHR    512
#define NBLOCKS ((NTETS + BM - 1) / BM)
#define SUBS    10        // K=64 sub-chunks (2 per gather slot)
#define SUBW    16384     // W bytes per sub-chunk (16 frags x 1KB)
#define FBLKS   (NTETS * FEATS / 8 / 256)   // 12500 fimg-convert blocks
#define WBLKS   320                          // W-frag blocks

typedef __attribute__((ext_vector_type(8))) short  short8v;
typedef __attribute__((ext_vector_type(4))) float  f32x4;

static __device__ __forceinline__ unsigned short bf16_rne(float f) {
  union { float f; unsigned u; } v; v.f = f;
  unsigned r = v.u + 0x7FFFu + ((v.u >> 16) & 1u);
  return (unsigned short)(r >> 16);
}

static __device__ __forceinline__ void gload_lds16(const void* g, void* l) {
  __builtin_amdgcn_global_load_lds(
      (const __attribute__((address_space(1))) unsigned int*)g,
      (__attribute__((address_space(3))) unsigned int*)l, 16, 0, 0);
}

// ONE prep kernel, three independent block ranges:
//   [0, FBLKS)           : feat fp32 -> bf16 fimg (nt loads keep feat out of L3)
//   [FBLKS, FBLKS+WBLKS) : W fp32 -> fragment-ordered bf16 image
//   [FBLKS+WBLKS]        : int64-vs-int32 neighbor detect
// W image [g][kk][ns8][lane64][e8]: byte ((g*4+kk)*8+ns)*1024 + lane*16 is
// lane's mfma_16x16x32 B-fragment (n = ns*16+(lane&15), k = g*128+kk*32+(lane>>4)*8+e).
__global__ __launch_bounds__(256) void prep_all_k(
    const float* __restrict__ feat, unsigned short* __restrict__ fimg,
    const float* __restrict__ W, unsigned short* __restrict__ wf,
    const int* __restrict__ nbr, int* __restrict__ mode)
{
  int b = blockIdx.x;
  if (b < FBLKS) {
    size_t i = ((size_t)b * 256 + threadIdx.x) * 8;
    f32x4 a = __builtin_nontemporal_load((const f32x4*)(feat + i));
    f32x4 c = __builtin_nontemporal_load((const f32x4*)(feat + i + 4));
    short8v v;
    v[0] = (short)bf16_rne(a[0]); v[1] = (short)bf16_rne(a[1]);
    v[2] = (short)bf16_rne(a[2]); v[3] = (short)bf16_rne(a[3]);
    v[4] = (short)bf16_rne(c[0]); v[5] = (short)bf16_rne(c[1]);
    v[6] = (short)bf16_rne(c[2]); v[7] = (short)bf16_rne(c[3]);
    *(short8v*)(fimg + i) = v;
    return;
  }
  if (b < FBLKS + WBLKS) {
    int id = (b - FBLKS) * 256 + threadIdx.x;   // WBLKS*256 == NG*16384 exactly
    int e  = id & 7;
    int l6 = (id >> 3) & 63;
    int ns = (id >> 9) & 7;
    int kk = (id >> 12) & 3;
    int g  = id >> 14;
    int n = ns * 16 + (l6 & 15);
    int k = g * 128 + kk * 32 + (l6 >> 4) * 8 + e;
    wf[id] = bf16_rne(W[n * (NG * FEATS) + k]);
    return;
  }
  {
    int t = threadIdx.x;
    if (t < 64) {
      int nz = 0;
      for (int i = t; i < 4096; i += 64) nz |= nbr[2 * i + 1];
      unsigned long long any = __ballot(nz != 0);
      if (t == 0) mode[0] = (any == 0ULL) ? 1 : 0;   // 1 => int64 indices
    }
  }
}

__global__ __launch_bounds__(NTHR, 6) void conv_k(
    const unsigned short* __restrict__ fimg, const int* __restrict__ nbr,
    const float* __restrict__ bias, const unsigned short* __restrict__ wf,
    const int* __restrict__ mode, float* __restrict__ out)
{
  __shared__ __align__(16) char wtile[3][SUBW];   // W sub-chunks, triple-buffered ring
  __shared__ unsigned srcoff[NG][BM];

  const int t    = threadIdx.x;
  const int row0 = blockIdx.x * BM;
  const int lane = t & 63;
  const int wv   = t >> 6;          // 8 waves; wave wv owns rows [wv*16, wv*16+16)
  const int lr   = lane & 15;
  const int lk   = lane >> 4;

  // ---- per-block source byte-offsets into fimg ----
  {
    const bool m64 = (mode[0] != 0);
    for (int e = t; e < NG * BM; e += NTHR) {
      int g = e >> 7, r = e & (BM - 1);
      int gr = row0 + r;
      int s = 0;
      if (gr < NTETS) {
        if (g == 0) s = gr;
        else {
          size_t idx = (size_t)gr * 4 + (g - 1);
          s = m64 ? nbr[2 * idx] : nbr[idx];
          if ((unsigned)s >= (unsigned)NTETS) s = 0;
        }
      }
      srcoff[g][r] = (unsigned)s * 256u;
    }
  }
  __syncthreads();

  // lane l's A-fragment: row (wv*16 + (l&15)), bytes [kk*64 + (l>>4)*16, +16).
  const char* fimgc = (const char*)fimg;
  unsigned aoff[NG];
#pragma unroll
  for (int g = 0; g < NG; ++g)
    aoff[g] = srcoff[g][wv * 16 + lr] + (unsigned)(lk * 16);

  const f32x4 zero = {0.f, 0.f, 0.f, 0.f};
  f32x4 acc[8];
#pragma unroll
  for (int i = 0; i < 8; ++i) acc[i] = zero;

  short8v a[3][2];   // A-fragment ring [sub%3][kklo]

#define SB() __builtin_amdgcn_sched_barrier(0)

  // sub ss covers k-slices kk = 2*(ss&1) + {0,1} of gather slot g = ss>>1
#define A_ISSUE(ss) do {                                                          \
    a[(ss) % 3][0] = *(const short8v*)(fimgc + aoff[(ss) >> 1] +                  \
                                       (((ss) & 1) * 2 + 0) * 64);                \
    a[(ss) % 3][1] = *(const short8v*)(fimgc + aoff[(ss) >> 1] +                  \
                                       (((ss) & 1) * 2 + 1) * 64);                \
  } while (0)

  // wave stages 2KB of the 16KB sub-chunk; LDS dest wave-uniform, src per-lane
#define W_ISSUE(ss) do {                                                          \
    const char* ws_ = (const char*)wf + (size_t)(ss) * SUBW + wv * 2048 +         \
                      (lane << 4);                                                \
    char* wd_ = &wtile[(ss) % 3][wv * 2048];                                      \
    gload_lds16(ws_, wd_);                                                        \
    gload_lds16(ws_ + 1024, wd_ + 1024);                                          \
  } while (0)

  // ---- prologue: queue = [W0,A0,W1,A1]; retire W0,A0 ----
  W_ISSUE(0); SB();
  A_ISSUE(0); SB();
  W_ISSUE(1); SB();
  A_ISSUE(1); SB();
  asm volatile("s_waitcnt vmcnt(4)" ::: "memory");
  SB();
  __builtin_amdgcn_s_barrier();

#pragma unroll
  for (int s = 0; s < SUBS; ++s) {
    // issue 2-ahead: W into ring slot (s+2)%3, A into reg ring slot (s+2)%3
    if (s + 2 < SUBS) {
      W_ISSUE(s + 2); SB();
      A_ISSUE(s + 2); SB();
    }
    // compute sub s from wtile[s%3] (b-LDS waits are compiler-counted)
    {
      short8v b[8];
#pragma unroll
      for (int ns = 0; ns < 8; ++ns)
        b[ns] = *(const short8v*)(&wtile[s % 3][ns * 1024 + (lane << 4)]);
#pragma unroll
      for (int ns = 0; ns < 8; ++ns)
        acc[ns] = __builtin_amdgcn_mfma_f32_16x16x32_bf16(a[s % 3][0], b[ns], acc[ns], 0, 0, 0);
#pragma unroll
      for (int ns = 0; ns < 8; ++ns)
        b[ns] = *(const short8v*)(&wtile[s % 3][(8 + ns) * 1024 + (lane << 4)]);
#pragma unroll
      for (int ns = 0; ns < 8; ++ns)
        acc[ns] = __builtin_amdgcn_mfma_f32_16x16x32_bf16(a[s % 3][1], b[ns], acc[ns], 0, 0, 0);
    }
    SB();
    // retire {W(s+1), A(s+1)} (leaves {W(s+2), A(s+2)} in flight); publish via barrier
    if (s + 1 < SUBS) {
      if (s + 2 < SUBS) asm volatile("s_waitcnt vmcnt(4)" ::: "memory");
      else              asm volatile("s_waitcnt vmcnt(0)" ::: "memory");
      SB();
      __builtin_amdgcn_s_barrier();
    }
  }

  // ---- epilogue: bias + relu + nt fp32 store (C: col=lane&15, row=(lane>>4)*4+reg) ----
#pragma unroll
  for (int ns = 0; ns < 8; ++ns) {
    const int col = ns * 16 + lr;
    const float bv = bias[col];
    const int rbase = row0 + wv * 16 + lk * 4;
#pragma unroll
    for (int i = 0; i < 4; ++i) {
      int r = rbase + i;
      if (r < NTETS) {
        float vv = acc[ns][i] + bv;
        vv = vv > 0.f ? vv : 0.f;
        __builtin_nontemporal_store(vv, &out[(size_t)r * OUTF + col]);
      }
    }
  }
#undef A_ISSUE
#undef W_ISSUE
#undef SB
}

extern "C" void kernel_launch(void* const* d_in, const int* in_sizes, int n_in,
                              void* d_out, int out_size, void* d_ws, size_t ws_size,
                              hipStream_t stream) {
  const float* feat = (const float*)d_in[0];
  const int*   nbr  = (const int*)d_in[1];
  const float* W    = (const float*)d_in[2];
  const float* bias = (const float*)d_in[3];
  float* out = (float*)d_out;

  int* mode = (int*)d_ws;
  unsigned short* wf   = (unsigned short*)((char*)d_ws + 1024);       // 160 KB frag image
  unsigned short* fimg = (unsigned short*)((char*)d_ws + 164864);     // 51.2 MB bf16 features

  prep_all_k<<<FBLKS + WBLKS + 1, 256, 0, stream>>>(feat, fimg, W, wf, nbr, mode);
  conv_k<<<NBLOCKS, NTHR, 0, stream>>>(fimg, nbr, bias, wf, mode, out);
}